// Round 8
// baseline (104.051 us; speedup 1.0000x reference)
//
#include <hip/hip_runtime.h>
#include <math.h>

#define MAX_SEQ   2048
#define NUM_HEADS 32
#define NUM_KV    4
#define HEAD_DIM  256
#define HIDDEN    4096
#define ROT_DIM   64
#define GROUPS    8           // NUM_HEADS / NUM_KV
#define SCALE     0.0625f     // 1/sqrt(256)
#define CHUNK     32
#define NCHUNK    (MAX_SEQ / CHUNK)   // 64

typedef float f4 __attribute__((ext_vector_type(4)));

__device__ inline f4 ld4(const float* p) {
    return *reinterpret_cast<const f4*>(p);
}

// ---------------------------------------------------------------------------
// Kernel 1: fused QKV GEMV, wave-per-row.  x staged in LDS once per block so
// the inner loop has ONE global stream (weights) + one LDS read.
// Block 4608 computes the RoPE table (f64, once).
// rows 0..16383 -> qg, 16384..17407 -> k_raw, 17408..18431 -> v_raw.
// ---------------------------------------------------------------------------
__global__ __launch_bounds__(256) void gemv_qkv(
    const float* __restrict__ x,
    const float* __restrict__ qw,   // 16384 x 4096
    const float* __restrict__ kw,   // 1024 x 4096
    const float* __restrict__ vw,   // 1024 x 4096
    const int*   __restrict__ posp,
    float* __restrict__ out,        // 18432
    float* __restrict__ tab)        // 64: cos|sin
{
    if (blockIdx.x == 4608) {       // RoPE table block
        const int i = threadIdx.x;
        if (i < 32) {
            const double inv_freq = pow(10000000.0, -(double)i / 32.0);
            const double ang = (double)posp[0] * inv_freq;
            tab[i]      = (float)cos(ang);
            tab[i + 32] = (float)sin(ang);
        }
        return;
    }

    __shared__ __align__(16) float xs[HIDDEN];   // 16 KB
    const int tid = threadIdx.x;
#pragma unroll
    for (int i = 0; i < 4; ++i) {
        const int idx = i * 1024 + tid * 4;
        *reinterpret_cast<f4*>(&xs[idx]) = ld4(x + idx);
    }
    __syncthreads();

    const int wave = tid >> 6;
    const int lane = tid & 63;
    const int row  = blockIdx.x * 4 + wave;

    const float* w;
    if (row < 16384)      w = qw + (size_t)row * HIDDEN;
    else if (row < 17408) w = kw + (size_t)(row - 16384) * HIDDEN;
    else                  w = vw + (size_t)(row - 17408) * HIDDEN;

    float acc = 0.f;
#pragma unroll
    for (int it = 0; it < HIDDEN / 256; ++it) {          // 16 iters
        const int idx = it * 256 + lane * 4;
        f4 wv = ld4(w + idx);
        f4 xv = *reinterpret_cast<const f4*>(&xs[idx]);
        acc += wv[0] * xv[0] + wv[1] * xv[1] + wv[2] * xv[2] + wv[3] * xv[3];
    }
#pragma unroll
    for (int off = 32; off >= 1; off >>= 1) acc += __shfl_xor(acc, off);
    if (lane == 0) out[row] = acc;
}

// ---------------------------------------------------------------------------
// Kernel 2: fused {RMSNorm + RoPE-from-table} + flash-decode partials.
// grid = (NUM_KV, NCHUNK), 256 threads.  (unchanged from round 6)
// ---------------------------------------------------------------------------
__global__ __launch_bounds__(256) void attn_partial(
    const float* __restrict__ qkv,      // qg[16384] | k_raw[1024] | v_raw[1024]
    const float* __restrict__ qnw,
    const float* __restrict__ knw,
    const float* __restrict__ kcache,   // 4*2048*256
    const float* __restrict__ vcache,
    const float* __restrict__ tab,      // 64: cos|sin
    const int*   __restrict__ posp,
    float* __restrict__ part_m,         // 32*NCHUNK
    float* __restrict__ part_l,         // 32*NCHUNK
    float* __restrict__ part_acc)       // 32*NCHUNK*256
{
    const int kv  = blockIdx.x;
    const int c   = blockIdx.y;
    const int pos = posp[0];
    const int s0  = c * CHUNK;
    const int tid = threadIdx.x;

    if (s0 > pos) {                       // empty chunk: mark all 8 heads
        if (tid == 0) {
#pragma unroll
            for (int g = 0; g < GROUPS; ++g) {
                const int pid = (kv * GROUPS + g) * NCHUNK + c;
                part_m[pid] = -1e30f; part_l[pid] = 0.f;
            }
        }
        return;
    }
    const int s1 = min(s0 + CHUNK, pos + 1);

    const int lane = tid & 63;
    const int wave = tid >> 6;
    const int d    = tid;

    // ---- fused norm: 8 q heads + 1 k head (index 8) ----
    float vals[9];
#pragma unroll
    for (int g = 0; g < GROUPS; ++g)
        vals[g] = qkv[(kv * GROUPS + g) * 512 + d];
    vals[8] = qkv[16384 + kv * HEAD_DIM + d];

    __shared__ float ssred[9][4];
    {
        float sq[9];
#pragma unroll
        for (int g = 0; g < 9; ++g) sq[g] = vals[g] * vals[g];
#pragma unroll
        for (int off = 32; off >= 1; off >>= 1) {
#pragma unroll
            for (int g = 0; g < 9; ++g) sq[g] += __shfl_xor(sq[g], off);
        }
        if (lane == 0) {
#pragma unroll
            for (int g = 0; g < 9; ++g) ssred[g][wave] = sq[g];
        }
    }
    __syncthreads();

    __shared__ __align__(16) float qn[9][HEAD_DIM];
    {
        const float qw_ = qnw[d];
        const float kw_ = knw[d];
#pragma unroll
        for (int g = 0; g < 9; ++g) {
            const float tot  = ssred[g][0] + ssred[g][1] + ssred[g][2] + ssred[g][3];
            const float norm = rsqrtf(tot * (1.0f / HEAD_DIM) + 1e-6f);
            qn[g][d] = vals[g] * norm * (g < 8 ? qw_ : kw_);
        }
    }
    __syncthreads();

    // ---- RoPE from table (barrier-safe: compute all, write rot lanes) ----
    {
        const bool rot = (d < ROT_DIM);
        const int  i   = d & 31;
        const float co = tab[i];
        const float si = tab[i + 32];
        float rv[9];
#pragma unroll
        for (int g = 0; g < 9; ++g) {
            const float x1 = qn[g][i];
            const float x2 = qn[g][i + 32];
            rv[g] = (d < 32) ? (x1 * co - x2 * si) : (x2 * co + x1 * si);
        }
        __syncthreads();
        if (rot) {
#pragma unroll
            for (int g = 0; g < 9; ++g) qn[g][d] = rv[g];
        }
        __syncthreads();
    }

    const float* kbase = kcache + (size_t)kv * MAX_SEQ * HEAD_DIM;
    const float* vbase = vcache + (size_t)kv * MAX_SEQ * HEAD_DIM;

    // q fragments for all 8 heads (from LDS, once)
    f4 q8[GROUPS];
#pragma unroll
    for (int g = 0; g < GROUPS; ++g)
        q8[g] = *reinterpret_cast<const f4*>(&qn[g][lane * 4]);

    __shared__ float sc[GROUPS][CHUNK];   // raw scores
    __shared__ __align__(16) float pl[GROUPS][CHUNK];   // exp(score - m)
    __shared__ float mh[GROUPS], lh[GROUPS];

    // ---- score phase: wave handles 8 contiguous positions, prefetch K ----
    {
        const int i0 = wave * 8;
        f4 kvec[8];
#pragma unroll
        for (int j = 0; j < 8; ++j) {
            const int s = s0 + i0 + j;
            if (s < pos) kvec[j] = ld4(kbase + (size_t)s * HEAD_DIM + lane * 4);
            else         kvec[j] = *reinterpret_cast<const f4*>(&qn[8][lane * 4]);
        }
#pragma unroll
        for (int j = 0; j < 8; ++j) {
            const int s = s0 + i0 + j;
            const bool valid = (s < s1);
            float part[GROUPS];
#pragma unroll
            for (int g = 0; g < GROUPS; ++g) {
                f4 t = q8[g] * kvec[j];
                part[g] = t[0] + t[1] + t[2] + t[3];
            }
#pragma unroll
            for (int off = 32; off >= 1; off >>= 1) {
#pragma unroll
                for (int g = 0; g < GROUPS; ++g)
                    part[g] += __shfl_xor(part[g], off);
            }
            if (lane == 0) {
#pragma unroll
                for (int g = 0; g < GROUPS; ++g)
                    sc[g][i0 + j] = valid ? part[g] * SCALE : -1e30f;
            }
        }
    }
    __syncthreads();

    // ---- softmax partials: thread t -> (head t>>5, pos t&31) ----
    {
        const int h = tid >> 5;           // 0..7
        const int j = tid & 31;           // 0..31 == CHUNK
        float v = sc[h][j];
        float m = v;
#pragma unroll
        for (int off = 16; off >= 1; off >>= 1)
            m = fmaxf(m, __shfl_xor(m, off));   // stays within 32-group
        const float p = expf(v - m);            // -1e30 - m -> 0
        pl[h][j] = p;
        float ls = p;
#pragma unroll
        for (int off = 16; off >= 1; off >>= 1)
            ls += __shfl_xor(ls, off);
        if (j == 0) { mh[h] = m; lh[h] = ls; }
    }
    __syncthreads();

    // ---- PV phase: fully unrolled, clamped addresses (pl==0 masks junk) ----
    float acc[GROUPS];
#pragma unroll
    for (int g = 0; g < GROUPS; ++g) acc[g] = 0.f;
    const float* vnew = qkv + 17408 + kv * HEAD_DIM;
#pragma unroll
    for (int i4 = 0; i4 < CHUNK / 4; ++i4) {
        float vv[4];
#pragma unroll
        for (int u = 0; u < 4; ++u) {
            const int s = s0 + i4 * 4 + u;
            vv[u] = (s < pos) ? vbase[(size_t)s * HEAD_DIM + d] : vnew[d];
        }
        f4 p4[GROUPS];
#pragma unroll
        for (int g = 0; g < GROUPS; ++g)
            p4[g] = *reinterpret_cast<const f4*>(&pl[g][i4 * 4]);
#pragma unroll
        for (int u = 0; u < 4; ++u) {
#pragma unroll
            for (int g = 0; g < GROUPS; ++g)
                acc[g] += p4[g][u] * vv[u];
        }
    }
#pragma unroll
    for (int g = 0; g < GROUPS; ++g) {
        const int pid = (kv * GROUPS + g) * NCHUNK + c;
        part_acc[(size_t)pid * HEAD_DIM + d] = acc[g];
        if (tid == 0) { part_m[pid] = mh[g]; part_l[pid] = lh[g]; }
    }
}

// ---------------------------------------------------------------------------
// Kernel 3: combine partials across chunks + apply sigmoid gate.
// Branchless (empty chunks -> w = 0).  (unchanged from round 6)
// ---------------------------------------------------------------------------
__global__ __launch_bounds__(256) void attn_combine(
    const float* __restrict__ part_m,
    const float* __restrict__ part_l,
    const float* __restrict__ part_acc,
    const float* __restrict__ qkv,      // gate at h*512 + 256 + d
    float* __restrict__ attn_gated)     // 8192
{
    const int h = blockIdx.x;
    const int d = threadIdx.x;

    float M = -1e30f;
#pragma unroll 8
    for (int c = 0; c < NCHUNK; ++c) M = fmaxf(M, part_m[h * NCHUNK + c]);

    float L = 0.f, acc = 0.f;
#pragma unroll 8
    for (int c = 0; c < NCHUNK; ++c) {
        const float w = expf(part_m[h * NCHUNK + c] - M);   // 0 for empty
        L   += part_l[h * NCHUNK + c] * w;
        acc += part_acc[(size_t)(h * NCHUNK + c) * HEAD_DIM + d] * w;
    }
    const float o   = acc / L;
    const float g   = qkv[h * 512 + 256 + d];
    const float sig = 1.0f / (1.0f + expf(-g));
    attn_gated[h * HEAD_DIM + d] = o * sig;
}

// ---------------------------------------------------------------------------
// Kernel 4: O-projection GEMV, wave-per-row.  vec staged in LDS once per
// block (32 KB) so the inner loop has ONE global stream.
// ---------------------------------------------------------------------------
__global__ __launch_bounds__(256) void gemv_o(
    const float* __restrict__ vec,      // 8192 gated attention output
    const float* __restrict__ w,        // 4096 x 8192
    float* __restrict__ out)            // 4096
{
    __shared__ __align__(16) float xs[8192];   // 32 KB
    const int tid = threadIdx.x;
#pragma unroll
    for (int i = 0; i < 8; ++i) {
        const int idx = i * 1024 + tid * 4;
        *reinterpret_cast<f4*>(&xs[idx]) = ld4(vec + idx);
    }
    __syncthreads();

    const int wave = tid >> 6;
    const int lane = tid & 63;
    const int row  = blockIdx.x * 4 + wave;
    const float* wr = w + (size_t)row * 8192;

    float acc = 0.f;
#pragma unroll
    for (int it = 0; it < 8192 / 256; ++it) {            // 32 iters
        const int idx = it * 256 + lane * 4;
        f4 wv = ld4(wr + idx);
        f4 xv = *reinterpret_cast<const f4*>(&xs[idx]);
        acc += wv[0] * xv[0] + wv[1] * xv[1] + wv[2] * xv[2] + wv[3] * xv[3];
    }
#pragma unroll
    for (int off = 32; off >= 1; off >>= 1) acc += __shfl_xor(acc, off);
    if (lane == 0) out[row] = acc;
}

// ---------------------------------------------------------------------------
extern "C" void kernel_launch(void* const* d_in, const int* in_sizes, int n_in,
                              void* d_out, int out_size, void* d_ws, size_t ws_size,
                              hipStream_t stream) {
    const float* x        = (const float*)d_in[0];
    const int*   position = (const int*)  d_in[1];
    // d_in[2] mask, d_in[5] onehot: derived from position on-device instead.
    const float* k_cache  = (const float*)d_in[3];
    const float* v_cache  = (const float*)d_in[4];
    const float* q_proj_w = (const float*)d_in[6];
    const float* k_proj_w = (const float*)d_in[7];
    const float* v_proj_w = (const float*)d_in[8];
    const float* o_proj_w = (const float*)d_in[9];
    const float* q_norm_w = (const float*)d_in[10];
    const float* k_norm_w = (const float*)d_in[11];
    float* out = (float*)d_out;

    float* ws         = (float*)d_ws;
    float* qkv        = ws;                  // 18432  (qg | k_raw | v_raw)
    float* tab        = ws + 18432;          // 64
    float* part_m     = ws + 18496;          // 2048
    float* part_l     = ws + 20544;          // 2048
    float* part_acc   = ws + 22592;          // 524288
    float* attn_gated = ws + 546880;         // 8192

    gemv_qkv<<<4609, 256, 0, stream>>>(x, q_proj_w, k_proj_w, v_proj_w,
                                       position, qkv, tab);
    dim3 g2(NUM_KV, NCHUNK);
    attn_partial<<<g2, 256, 0, stream>>>(qkv, q_norm_w, k_norm_w,
                                         k_cache, v_cache, tab, position,
                                         part_m, part_l, part_acc);
    attn_combine<<<NUM_HEADS, 256, 0, stream>>>(part_m, part_l, part_acc, qkv,
                                                attn_gated);
    gemv_o<<<1024, 256, 0, stream>>>(attn_gated, o_proj_w, out);
}

// Round 10
// 103.447 us; speedup vs baseline: 1.0058x; 1.0058x over previous
//
#include <hip/hip_runtime.h>
#include <math.h>

#define MAX_SEQ   2048
#define NUM_HEADS 32
#define NUM_KV    4
#define HEAD_DIM  256
#define HIDDEN    4096
#define ROT_DIM   64
#define GROUPS    8           // NUM_HEADS / NUM_KV
#define SCALE     0.0625f     // 1/sqrt(256)
#define CHUNK     32
#define NCHUNK    (MAX_SEQ / CHUNK)   // 64

typedef float f4 __attribute__((ext_vector_type(4)));

__device__ inline f4 ld4(const float* p) {
    return *reinterpret_cast<const f4*>(p);
}

// ---------------------------------------------------------------------------
// Kernel 1: fused QKV GEMV, wave-per-row, x held in 16 f4 REGISTERS so the
// inner loop is a SINGLE global stream (weights) + FMAs.  Block 4608
// computes the RoPE table (f64, once).
// rows 0..16383 -> qg, 16384..17407 -> k_raw, 17408..18431 -> v_raw.
// ---------------------------------------------------------------------------
__global__ __launch_bounds__(256, 2) void gemv_qkv(
    const float* __restrict__ x,
    const float* __restrict__ qw,   // 16384 x 4096
    const float* __restrict__ kw,   // 1024 x 4096
    const float* __restrict__ vw,   // 1024 x 4096
    const int*   __restrict__ posp,
    float* __restrict__ out,        // 18432
    float* __restrict__ tab)        // 64: cos|sin
{
    if (blockIdx.x == 4608) {       // RoPE table block
        const int i = threadIdx.x;
        if (i < 32) {
            const double inv_freq = pow(10000000.0, -(double)i / 32.0);
            const double ang = (double)posp[0] * inv_freq;
            tab[i]      = (float)cos(ang);
            tab[i + 32] = (float)sin(ang);
        }
        return;
    }
    const int wave = threadIdx.x >> 6;
    const int lane = threadIdx.x & 63;
    const int row  = blockIdx.x * 4 + wave;

    // x -> registers: lane l holds x[it*256 + l*4 .. +3] for it = 0..15
    f4 xr[16];
#pragma unroll
    for (int it = 0; it < 16; ++it) xr[it] = ld4(x + it * 256 + lane * 4);

    const float* w;
    if (row < 16384)      w = qw + (size_t)row * HIDDEN;
    else if (row < 17408) w = kw + (size_t)(row - 16384) * HIDDEN;
    else                  w = vw + (size_t)(row - 17408) * HIDDEN;

    float acc = 0.f;
#pragma unroll
    for (int it = 0; it < 16; ++it) {                    // single weight stream
        f4 wv = ld4(w + it * 256 + lane * 4);
        acc += wv[0]*xr[it][0] + wv[1]*xr[it][1] + wv[2]*xr[it][2] + wv[3]*xr[it][3];
    }
#pragma unroll
    for (int off = 32; off >= 1; off >>= 1) acc += __shfl_xor(acc, off);
    if (lane == 0) out[row] = acc;
}

// ---------------------------------------------------------------------------
// Kernel 2: fused {RMSNorm + RoPE-from-table} + flash-decode partials.
// (unchanged from round 6)
// ---------------------------------------------------------------------------
__global__ __launch_bounds__(256) void attn_partial(
    const float* __restrict__ qkv,      // qg[16384] | k_raw[1024] | v_raw[1024]
    const float* __restrict__ qnw,
    const float* __restrict__ knw,
    const float* __restrict__ kcache,   // 4*2048*256
    const float* __restrict__ vcache,
    const float* __restrict__ tab,      // 64: cos|sin
    const int*   __restrict__ posp,
    float* __restrict__ part_m,         // 32*NCHUNK
    float* __restrict__ part_l,         // 32*NCHUNK
    float* __restrict__ part_acc)       // 32*NCHUNK*256
{
    const int kv  = blockIdx.x;
    const int c   = blockIdx.y;
    const int pos = posp[0];
    const int s0  = c * CHUNK;
    const int tid = threadIdx.x;

    if (s0 > pos) {                       // empty chunk: mark all 8 heads
        if (tid == 0) {
#pragma unroll
            for (int g = 0; g < GROUPS; ++g) {
                const int pid = (kv * GROUPS + g) * NCHUNK + c;
                part_m[pid] = -1e30f; part_l[pid] = 0.f;
            }
        }
        return;
    }
    const int s1 = min(s0 + CHUNK, pos + 1);

    const int lane = tid & 63;
    const int wave = tid >> 6;
    const int d    = tid;

    // ---- fused norm: 8 q heads + 1 k head (index 8) ----
    float vals[9];
#pragma unroll
    for (int g = 0; g < GROUPS; ++g)
        vals[g] = qkv[(kv * GROUPS + g) * 512 + d];
    vals[8] = qkv[16384 + kv * HEAD_DIM + d];

    __shared__ float ssred[9][4];
    {
        float sq[9];
#pragma unroll
        for (int g = 0; g < 9; ++g) sq[g] = vals[g] * vals[g];
#pragma unroll
        for (int off = 32; off >= 1; off >>= 1) {
#pragma unroll
            for (int g = 0; g < 9; ++g) sq[g] += __shfl_xor(sq[g], off);
        }
        if (lane == 0) {
#pragma unroll
            for (int g = 0; g < 9; ++g) ssred[g][wave] = sq[g];
        }
    }
    __syncthreads();

    __shared__ __align__(16) float qn[9][HEAD_DIM];
    {
        const float qw_ = qnw[d];
        const float kw_ = knw[d];
#pragma unroll
        for (int g = 0; g < 9; ++g) {
            const float tot  = ssred[g][0] + ssred[g][1] + ssred[g][2] + ssred[g][3];
            const float norm = rsqrtf(tot * (1.0f / HEAD_DIM) + 1e-6f);
            qn[g][d] = vals[g] * norm * (g < 8 ? qw_ : kw_);
        }
    }
    __syncthreads();

    // ---- RoPE from table (barrier-safe: compute all, write rot lanes) ----
    {
        const bool rot = (d < ROT_DIM);
        const int  i   = d & 31;
        const float co = tab[i];
        const float si = tab[i + 32];
        float rv[9];
#pragma unroll
        for (int g = 0; g < 9; ++g) {
            const float x1 = qn[g][i];
            const float x2 = qn[g][i + 32];
            rv[g] = (d < 32) ? (x1 * co - x2 * si) : (x2 * co + x1 * si);
        }
        __syncthreads();
        if (rot) {
#pragma unroll
            for (int g = 0; g < 9; ++g) qn[g][d] = rv[g];
        }
        __syncthreads();
    }

    const float* kbase = kcache + (size_t)kv * MAX_SEQ * HEAD_DIM;
    const float* vbase = vcache + (size_t)kv * MAX_SEQ * HEAD_DIM;

    // q fragments for all 8 heads (from LDS, once)
    f4 q8[GROUPS];
#pragma unroll
    for (int g = 0; g < GROUPS; ++g)
        q8[g] = *reinterpret_cast<const f4*>(&qn[g][lane * 4]);

    __shared__ float sc[GROUPS][CHUNK];   // raw scores
    __shared__ __align__(16) float pl[GROUPS][CHUNK];   // exp(score - m)
    __shared__ float mh[GROUPS], lh[GROUPS];

    // ---- score phase: wave handles 8 contiguous positions, prefetch K ----
    {
        const int i0 = wave * 8;
        f4 kvec[8];
#pragma unroll
        for (int j = 0; j < 8; ++j) {
            const int s = s0 + i0 + j;
            if (s < pos) kvec[j] = ld4(kbase + (size_t)s * HEAD_DIM + lane * 4);
            else         kvec[j] = *reinterpret_cast<const f4*>(&qn[8][lane * 4]);
        }
#pragma unroll
        for (int j = 0; j < 8; ++j) {
            const int s = s0 + i0 + j;
            const bool valid = (s < s1);
            float part[GROUPS];
#pragma unroll
            for (int g = 0; g < GROUPS; ++g) {
                f4 t = q8[g] * kvec[j];
                part[g] = t[0] + t[1] + t[2] + t[3];
            }
#pragma unroll
            for (int off = 32; off >= 1; off >>= 1) {
#pragma unroll
                for (int g = 0; g < GROUPS; ++g)
                    part[g] += __shfl_xor(part[g], off);
            }
            if (lane == 0) {
#pragma unroll
                for (int g = 0; g < GROUPS; ++g)
                    sc[g][i0 + j] = valid ? part[g] * SCALE : -1e30f;
            }
        }
    }
    __syncthreads();

    // ---- softmax partials: thread t -> (head t>>5, pos t&31) ----
    {
        const int h = tid >> 5;           // 0..7
        const int j = tid & 31;           // 0..31 == CHUNK
        float v = sc[h][j];
        float m = v;
#pragma unroll
        for (int off = 16; off >= 1; off >>= 1)
            m = fmaxf(m, __shfl_xor(m, off));   // stays within 32-group
        const float p = expf(v - m);            // -1e30 - m -> 0
        pl[h][j] = p;
        float ls = p;
#pragma unroll
        for (int off = 16; off >= 1; off >>= 1)
            ls += __shfl_xor(ls, off);
        if (j == 0) { mh[h] = m; lh[h] = ls; }
    }
    __syncthreads();

    // ---- PV phase: fully unrolled, clamped addresses (pl==0 masks junk) ----
    float acc[GROUPS];
#pragma unroll
    for (int g = 0; g < GROUPS; ++g) acc[g] = 0.f;
    const float* vnew = qkv + 17408 + kv * HEAD_DIM;
#pragma unroll
    for (int i4 = 0; i4 < CHUNK / 4; ++i4) {
        float vv[4];
#pragma unroll
        for (int u = 0; u < 4; ++u) {
            const int s = s0 + i4 * 4 + u;
            vv[u] = (s < pos) ? vbase[(size_t)s * HEAD_DIM + d] : vnew[d];
        }
        f4 p4[GROUPS];
#pragma unroll
        for (int g = 0; g < GROUPS; ++g)
            p4[g] = *reinterpret_cast<const f4*>(&pl[g][i4 * 4]);
#pragma unroll
        for (int u = 0; u < 4; ++u) {
#pragma unroll
            for (int g = 0; g < GROUPS; ++g)
                acc[g] += p4[g][u] * vv[u];
        }
    }
#pragma unroll
    for (int g = 0; g < GROUPS; ++g) {
        const int pid = (kv * GROUPS + g) * NCHUNK + c;
        part_acc[(size_t)pid * HEAD_DIM + d] = acc[g];
        if (tid == 0) { part_m[pid] = mh[g]; part_l[pid] = lh[g]; }
    }
}

// ---------------------------------------------------------------------------
// Kernel 3: combine partials across chunks + apply sigmoid gate.
// Branchless (empty chunks -> w = 0).  (unchanged from round 6)
// ---------------------------------------------------------------------------
__global__ __launch_bounds__(256) void attn_combine(
    const float* __restrict__ part_m,
    const float* __restrict__ part_l,
    const float* __restrict__ part_acc,
    const float* __restrict__ qkv,      // gate at h*512 + 256 + d
    float* __restrict__ attn_gated)     // 8192
{
    const int h = blockIdx.x;
    const int d = threadIdx.x;

    float M = -1e30f;
#pragma unroll 8
    for (int c = 0; c < NCHUNK; ++c) M = fmaxf(M, part_m[h * NCHUNK + c]);

    float L = 0.f, acc = 0.f;
#pragma unroll 8
    for (int c = 0; c < NCHUNK; ++c) {
        const float w = expf(part_m[h * NCHUNK + c] - M);   // 0 for empty
        L   += part_l[h * NCHUNK + c] * w;
        acc += part_acc[(size_t)(h * NCHUNK + c) * HEAD_DIM + d] * w;
    }
    const float o   = acc / L;
    const float g   = qkv[h * 512 + 256 + d];
    const float sig = 1.0f / (1.0f + expf(-g));
    attn_gated[h * HEAD_DIM + d] = o * sig;
}

// ---------------------------------------------------------------------------
// Kernel 4: O-projection GEMV.  Each wave owns a HALF-row (4 KB) with its
// vec-half in 16 f4 registers -> single weight stream.  2 rows per block;
// waves {0,1} -> row, waves {2,3} -> row+1; halves combined via LDS.
// FIX vs round 9: thread 128's row is ALREADY blockIdx.x*2+1 -> write
// out[row], not out[row+1].
// ---------------------------------------------------------------------------
__global__ __launch_bounds__(256, 2) void gemv_o(
    const float* __restrict__ vec,      // 8192 gated attention output
    const float* __restrict__ w,        // 4096 x 8192
    float* __restrict__ out)            // 4096
{
    const int tid  = threadIdx.x;
    const int wave = tid >> 6;
    const int lane = tid & 63;
    const int row  = blockIdx.x * 2 + (wave >> 1);   // waves 0,1 -> r0; 2,3 -> r0+1
    const int half = wave & 1;

    const float* xsrc = vec + half * 4096;
    f4 xr[16];
#pragma unroll
    for (int it = 0; it < 16; ++it) xr[it] = ld4(xsrc + it * 256 + lane * 4);

    const float* wr = w + (size_t)row * 8192 + half * 4096;
    float acc = 0.f;
#pragma unroll
    for (int it = 0; it < 16; ++it) {                    // single weight stream
        f4 wv = ld4(wr + it * 256 + lane * 4);
        acc += wv[0]*xr[it][0] + wv[1]*xr[it][1] + wv[2]*xr[it][2] + wv[3]*xr[it][3];
    }
#pragma unroll
    for (int off = 32; off >= 1; off >>= 1) acc += __shfl_xor(acc, off);

    __shared__ float red[4];
    if (lane == 0) red[wave] = acc;
    __syncthreads();
    if (tid == 0)   out[row] = red[0] + red[1];          // row = bid*2
    if (tid == 128) out[row] = red[2] + red[3];          // row = bid*2 + 1
}

// ---------------------------------------------------------------------------
extern "C" void kernel_launch(void* const* d_in, const int* in_sizes, int n_in,
                              void* d_out, int out_size, void* d_ws, size_t ws_size,
                              hipStream_t stream) {
    const float* x        = (const float*)d_in[0];
    const int*   position = (const int*)  d_in[1];
    // d_in[2] mask, d_in[5] onehot: derived from position on-device instead.
    const float* k_cache  = (const float*)d_in[3];
    const float* v_cache  = (const float*)d_in[4];
    const float* q_proj_w = (const float*)d_in[6];
    const float* k_proj_w = (const float*)d_in[7];
    const float* v_proj_w = (const float*)d_in[8];
    const float* o_proj_w = (const float*)d_in[9];
    const float* q_norm_w = (const float*)d_in[10];
    const float* k_norm_w = (const float*)d_in[11];
    float* out = (float*)d_out;

    float* ws         = (float*)d_ws;
    float* qkv        = ws;                  // 18432  (qg | k_raw | v_raw)
    float* tab        = ws + 18432;          // 64
    float* part_m     = ws + 18496;          // 2048
    float* part_l     = ws + 20544;          // 2048
    float* part_acc   = ws + 22592;          // 524288
    float* attn_gated = ws + 546880;         // 8192

    gemv_qkv<<<4609, 256, 0, stream>>>(x, q_proj_w, k_proj_w, v_proj_w,
                                       position, qkv, tab);
    dim3 g2(NUM_KV, NCHUNK);
    attn_partial<<<g2, 256, 0, stream>>>(qkv, q_norm_w, k_norm_w,
                                         k_cache, v_cache, tab, position,
                                         part_m, part_l, part_acc);
    attn_combine<<<NUM_HEADS, 256, 0, stream>>>(part_m, part_l, part_acc, qkv,
                                                attn_gated);
    gemv_o<<<2048, 256, 0, stream>>>(attn_gated, o_proj_w, out);
}

// Round 11
// 100.438 us; speedup vs baseline: 1.0360x; 1.0300x over previous
//
#include <hip/hip_runtime.h>
#include <math.h>

#define MAX_SEQ   2048
#define NUM_HEADS 32
#define NUM_KV    4
#define HEAD_DIM  256
#define HIDDEN    4096
#define ROT_DIM   64
#define GROUPS    8           // NUM_HEADS / NUM_KV
#define SCALE     0.0625f     // 1/sqrt(256)
#define CHUNK     32
#define NCHUNK    (MAX_SEQ / CHUNK)   // 64

typedef float f4 __attribute__((ext_vector_type(4)));

__device__ inline f4 ld4(const float* p) {
    return *reinterpret_cast<const f4*>(p);
}

// ---------------------------------------------------------------------------
// Kernel 1: fused QKV GEMV, wave-per-row, 16-deep unrolled float4 dual
// stream (round-6 proven form).  Block 4608 computes the RoPE table.
// rows 0..16383 -> qg, 16384..17407 -> k_raw, 17408..18431 -> v_raw.
// ---------------------------------------------------------------------------
__global__ __launch_bounds__(256) void gemv_qkv(
    const float* __restrict__ x,
    const float* __restrict__ qw,   // 16384 x 4096
    const float* __restrict__ kw,   // 1024 x 4096
    const float* __restrict__ vw,   // 1024 x 4096
    const int*   __restrict__ posp,
    float* __restrict__ out,        // 18432
    float* __restrict__ tab)        // 64: cos|sin
{
    if (blockIdx.x == 4608) {       // RoPE table block
        const int i = threadIdx.x;
        if (i < 32) {
            const double inv_freq = pow(10000000.0, -(double)i / 32.0);
            const double ang = (double)posp[0] * inv_freq;
            tab[i]      = (float)cos(ang);
            tab[i + 32] = (float)sin(ang);
        }
        return;
    }
    const int wave = threadIdx.x >> 6;
    const int lane = threadIdx.x & 63;
    const int row  = blockIdx.x * 4 + wave;

    const float* w;
    if (row < 16384)      w = qw + (size_t)row * HIDDEN;
    else if (row < 17408) w = kw + (size_t)(row - 16384) * HIDDEN;
    else                  w = vw + (size_t)(row - 17408) * HIDDEN;

    float acc = 0.f;
#pragma unroll
    for (int it = 0; it < HIDDEN / 256; ++it) {          // 16 iters
        const int idx = it * 256 + lane * 4;
        f4 wv = ld4(w + idx);
        f4 xv = ld4(x + idx);
        acc += wv[0] * xv[0] + wv[1] * xv[1] + wv[2] * xv[2] + wv[3] * xv[3];
    }
#pragma unroll
    for (int off = 32; off >= 1; off >>= 1) acc += __shfl_xor(acc, off);
    if (lane == 0) out[row] = acc;
}

// ---------------------------------------------------------------------------
// Kernel 2: fused {RMSNorm + RoPE-from-table} + flash-decode partials.
// CHANGE vs round 6: ALL K/V cache loads are issued BEFORE the norm/rope
// phase (clamped addresses, patched after RoPE) so their HBM/L3 latency
// hides under the norm math + barriers.  Position s == pos substitutes
// fresh k/v (caches NOT mutated).
// ---------------------------------------------------------------------------
__global__ __launch_bounds__(256) void attn_partial(
    const float* __restrict__ qkv,      // qg[16384] | k_raw[1024] | v_raw[1024]
    const float* __restrict__ qnw,
    const float* __restrict__ knw,
    const float* __restrict__ kcache,   // 4*2048*256
    const float* __restrict__ vcache,
    const float* __restrict__ tab,      // 64: cos|sin
    const int*   __restrict__ posp,
    float* __restrict__ part_m,         // 32*NCHUNK
    float* __restrict__ part_l,         // 32*NCHUNK
    float* __restrict__ part_acc)       // 32*NCHUNK*256
{
    const int kv  = blockIdx.x;
    const int c   = blockIdx.y;
    const int pos = posp[0];
    const int s0  = c * CHUNK;
    const int tid = threadIdx.x;

    if (s0 > pos) {                       // empty chunk: mark all 8 heads
        if (tid == 0) {
#pragma unroll
            for (int g = 0; g < GROUPS; ++g) {
                const int pid = (kv * GROUPS + g) * NCHUNK + c;
                part_m[pid] = -1e30f; part_l[pid] = 0.f;
            }
        }
        return;
    }
    const int s1 = min(s0 + CHUNK, pos + 1);

    const int lane = tid & 63;
    const int wave = tid >> 6;
    const int d    = tid;

    const float* kbase = kcache + (size_t)kv * MAX_SEQ * HEAD_DIM;
    const float* vbase = vcache + (size_t)kv * MAX_SEQ * HEAD_DIM;

    // ---- issue ALL independent global loads up front ----
    float vals[9];
#pragma unroll
    for (int g = 0; g < GROUPS; ++g)
        vals[g] = qkv[(kv * GROUPS + g) * 512 + d];
    vals[8] = qkv[16384 + kv * HEAD_DIM + d];
    const float vnew_d = qkv[17408 + kv * HEAD_DIM + d];

    // V rows for all 32 positions (clamped; patched after rope)
    float vpre[CHUNK];
#pragma unroll
    for (int u = 0; u < CHUNK; ++u) {
        const int s = s0 + u;
        const int srow = (s < pos) ? s : 0;
        vpre[u] = vbase[(size_t)srow * HEAD_DIM + d];
    }

    // K fragments: wave handles 8 contiguous positions (clamped; patched)
    const int i0 = wave * 8;
    f4 kpre[8];
#pragma unroll
    for (int j = 0; j < 8; ++j) {
        const int s = s0 + i0 + j;
        const int srow = (s < pos) ? s : 0;
        kpre[j] = ld4(kbase + (size_t)srow * HEAD_DIM + lane * 4);
    }

    // ---- norm (prefetch latency hides under this) ----
    __shared__ float ssred[9][4];
    {
        float sq[9];
#pragma unroll
        for (int g = 0; g < 9; ++g) sq[g] = vals[g] * vals[g];
#pragma unroll
        for (int off = 32; off >= 1; off >>= 1) {
#pragma unroll
            for (int g = 0; g < 9; ++g) sq[g] += __shfl_xor(sq[g], off);
        }
        if (lane == 0) {
#pragma unroll
            for (int g = 0; g < 9; ++g) ssred[g][wave] = sq[g];
        }
    }
    __syncthreads();

    __shared__ __align__(16) float qn[9][HEAD_DIM];
    {
        const float qw_ = qnw[d];
        const float kw_ = knw[d];
#pragma unroll
        for (int g = 0; g < 9; ++g) {
            const float tot  = ssred[g][0] + ssred[g][1] + ssred[g][2] + ssred[g][3];
            const float norm = rsqrtf(tot * (1.0f / HEAD_DIM) + 1e-6f);
            qn[g][d] = vals[g] * norm * (g < 8 ? qw_ : kw_);
        }
    }
    __syncthreads();

    // ---- RoPE from table (barrier-safe: compute all, write rot lanes) ----
    {
        const bool rot = (d < ROT_DIM);
        const int  i   = d & 31;
        const float co = tab[i];
        const float si = tab[i + 32];
        float rv[9];
#pragma unroll
        for (int g = 0; g < 9; ++g) {
            const float x1 = qn[g][i];
            const float x2 = qn[g][i + 32];
            rv[g] = (d < 32) ? (x1 * co - x2 * si) : (x2 * co + x1 * si);
        }
        __syncthreads();
        if (rot) {
#pragma unroll
            for (int g = 0; g < 9; ++g) qn[g][d] = rv[g];
        }
        __syncthreads();
    }

    // ---- patch prefetched values at/after position pos ----
#pragma unroll
    for (int u = 0; u < CHUNK; ++u)
        if (s0 + u >= pos) vpre[u] = vnew_d;
    const f4 kf4 = *reinterpret_cast<const f4*>(&qn[8][lane * 4]);
#pragma unroll
    for (int j = 0; j < 8; ++j)
        if (s0 + i0 + j >= pos) kpre[j] = kf4;

    // q fragments for all 8 heads (from LDS, once)
    f4 q8[GROUPS];
#pragma unroll
    for (int g = 0; g < GROUPS; ++g)
        q8[g] = *reinterpret_cast<const f4*>(&qn[g][lane * 4]);

    __shared__ float sc[GROUPS][CHUNK];   // raw scores
    __shared__ __align__(16) float pl[GROUPS][CHUNK];   // exp(score - m)
    __shared__ float mh[GROUPS], lh[GROUPS];

    // ---- score phase ----
#pragma unroll
    for (int j = 0; j < 8; ++j) {
        const int s = s0 + i0 + j;
        const bool valid = (s < s1);
        float part[GROUPS];
#pragma unroll
        for (int g = 0; g < GROUPS; ++g) {
            f4 t = q8[g] * kpre[j];
            part[g] = t[0] + t[1] + t[2] + t[3];
        }
#pragma unroll
        for (int off = 32; off >= 1; off >>= 1) {
#pragma unroll
            for (int g = 0; g < GROUPS; ++g)
                part[g] += __shfl_xor(part[g], off);
        }
        if (lane == 0) {
#pragma unroll
            for (int g = 0; g < GROUPS; ++g)
                sc[g][i0 + j] = valid ? part[g] * SCALE : -1e30f;
        }
    }
    __syncthreads();

    // ---- softmax partials: thread t -> (head t>>5, pos t&31) ----
    {
        const int h = tid >> 5;           // 0..7
        const int j = tid & 31;           // 0..31 == CHUNK
        float v = sc[h][j];
        float m = v;
#pragma unroll
        for (int off = 16; off >= 1; off >>= 1)
            m = fmaxf(m, __shfl_xor(m, off));   // stays within 32-group
        const float p = expf(v - m);            // -1e30 - m -> 0
        pl[h][j] = p;
        float ls = p;
#pragma unroll
        for (int off = 16; off >= 1; off >>= 1)
            ls += __shfl_xor(ls, off);
        if (j == 0) { mh[h] = m; lh[h] = ls; }
    }
    __syncthreads();

    // ---- PV phase: entirely register-resident V ----
    float acc[GROUPS];
#pragma unroll
    for (int g = 0; g < GROUPS; ++g) acc[g] = 0.f;
#pragma unroll
    for (int i4 = 0; i4 < CHUNK / 4; ++i4) {
        f4 p4[GROUPS];
#pragma unroll
        for (int g = 0; g < GROUPS; ++g)
            p4[g] = *reinterpret_cast<const f4*>(&pl[g][i4 * 4]);
#pragma unroll
        for (int u = 0; u < 4; ++u) {
#pragma unroll
            for (int g = 0; g < GROUPS; ++g)
                acc[g] += p4[g][u] * vpre[i4 * 4 + u];
        }
    }
#pragma unroll
    for (int g = 0; g < GROUPS; ++g) {
        const int pid = (kv * GROUPS + g) * NCHUNK + c;
        part_acc[(size_t)pid * HEAD_DIM + d] = acc[g];
        if (tid == 0) { part_m[pid] = mh[g]; part_l[pid] = lh[g]; }
    }
}

// ---------------------------------------------------------------------------
// Kernel 3: combine partials across chunks + apply sigmoid gate.
// Branchless (empty chunks -> w = 0).  (unchanged from round 6)
// ---------------------------------------------------------------------------
__global__ __launch_bounds__(256) void attn_combine(
    const float* __restrict__ part_m,
    const float* __restrict__ part_l,
    const float* __restrict__ part_acc,
    const float* __restrict__ qkv,      // gate at h*512 + 256 + d
    float* __restrict__ attn_gated)     // 8192
{
    const int h = blockIdx.x;
    const int d = threadIdx.x;

    float M = -1e30f;
#pragma unroll 8
    for (int c = 0; c < NCHUNK; ++c) M = fmaxf(M, part_m[h * NCHUNK + c]);

    float L = 0.f, acc = 0.f;
#pragma unroll 8
    for (int c = 0; c < NCHUNK; ++c) {
        const float w = expf(part_m[h * NCHUNK + c] - M);   // 0 for empty
        L   += part_l[h * NCHUNK + c] * w;
        acc += part_acc[(size_t)(h * NCHUNK + c) * HEAD_DIM + d] * w;
    }
    const float o   = acc / L;
    const float g   = qkv[h * 512 + 256 + d];
    const float sig = 1.0f / (1.0f + expf(-g));
    attn_gated[h * HEAD_DIM + d] = o * sig;
}

// ---------------------------------------------------------------------------
// Kernel 4: O-projection GEMV, wave-per-row, 32-deep unrolled dual stream
// (round-6 proven form).
// ---------------------------------------------------------------------------
__global__ __launch_bounds__(256) void gemv_o(
    const float* __restrict__ vec,      // 8192 gated attention output
    const float* __restrict__ w,        // 4096 x 8192
    float* __restrict__ out)            // 4096
{
    const int wave = threadIdx.x >> 6;
    const int lane = threadIdx.x & 63;
    const int row  = blockIdx.x * 4 + wave;
    const float* wr = w + (size_t)row * 8192;

    float acc = 0.f;
#pragma unroll
    for (int it = 0; it < 8192 / 256; ++it) {            // 32 iters
        const int idx = it * 256 + lane * 4;
        f4 wv = ld4(wr + idx);
        f4 xv = ld4(vec + idx);
        acc += wv[0] * xv[0] + wv[1] * xv[1] + wv[2] * xv[2] + wv[3] * xv[3];
    }
#pragma unroll
    for (int off = 32; off >= 1; off >>= 1) acc += __shfl_xor(acc, off);
    if (lane == 0) out[row] = acc;
}

// ---------------------------------------------------------------------------
extern "C" void kernel_launch(void* const* d_in, const int* in_sizes, int n_in,
                              void* d_out, int out_size, void* d_ws, size_t ws_size,
                              hipStream_t stream) {
    const float* x        = (const float*)d_in[0];
    const int*   position = (const int*)  d_in[1];
    // d_in[2] mask, d_in[5] onehot: derived from position on-device instead.
    const float* k_cache  = (const float*)d_in[3];
    const float* v_cache  = (const float*)d_in[4];
    const float* q_proj_w = (const float*)d_in[6];
    const float* k_proj_w = (const float*)d_in[7];
    const float* v_proj_w = (const float*)d_in[8];
    const float* o_proj_w = (const float*)d_in[9];
    const float* q_norm_w = (const float*)d_in[10];
    const float* k_norm_w = (const float*)d_in[11];
    float* out = (float*)d_out;

    float* ws         = (float*)d_ws;
    float* qkv        = ws;                  // 18432  (qg | k_raw | v_raw)
    float* tab        = ws + 18432;          // 64
    float* part_m     = ws + 18496;          // 2048
    float* part_l     = ws + 20544;          // 2048
    float* part_acc   = ws + 22592;          // 524288
    float* attn_gated = ws + 546880;         // 8192

    gemv_qkv<<<4609, 256, 0, stream>>>(x, q_proj_w, k_proj_w, v_proj_w,
                                       position, qkv, tab);
    dim3 g2(NUM_KV, NCHUNK);
    attn_partial<<<g2, 256, 0, stream>>>(qkv, q_norm_w, k_norm_w,
                                         k_cache, v_cache, tab, position,
                                         part_m, part_l, part_acc);
    attn_combine<<<NUM_HEADS, 256, 0, stream>>>(part_m, part_l, part_acc, qkv,
                                                attn_gated);
    gemv_o<<<1024, 256, 0, stream>>>(attn_gated, o_proj_w, out);
}